// Round 1
// baseline (2670.129 us; speedup 1.0000x reference)
//
#include <hip/hip_runtime.h>
#include <math.h>

#define SS 2048
#define BB 256
#define II 32
#define HH 64

__device__ __forceinline__ float sigm(float x) {
    return 1.f / (1.f + expf(-x));
}

__global__ __launch_bounds__(512, 2) void lstm_fused(
    const float* __restrict__ x,
    const float* __restrict__ h_in,
    const float* __restrict__ c_in,
    const float* __restrict__ Wih0, const float* __restrict__ Whh0,
    const float* __restrict__ bih0, const float* __restrict__ bhh0,
    const float* __restrict__ Wih1, const float* __restrict__ Whh1,
    const float* __restrict__ bih1, const float* __restrict__ bhh1,
    const float* __restrict__ Wh, const float* __restrict__ bh,
    float* __restrict__ out)
{
    // LDS: h state double-buffered, gate exchange, x staging (2 chunks of 64 steps)
    __shared__ __align__(16) float h0buf[2][64];
    __shared__ __align__(16) float h1buf[2][64];
    __shared__ __align__(16) float gates[2][256];
    __shared__ __align__(16) float xs[2][64][32];

    const int b    = blockIdx.x;
    const int tid  = threadIdx.x;
    const int g    = tid >> 8;        // 0: layer-0 gate group (tid 0..255), 1: layer-1 (256..511)
    const int j    = tid & 255;       // gate index within group
    const int wv   = (tid >> 6) & 3;  // wave-within-group: 0=i,1=f,2=g(tanh),3=o
    const int lane = tid & 63;

    // ---- weight preload into registers (rows of Wih / Whh for this thread's gate) ----
    float wx[64];   // L0: Wih0[j, 0:32] in wx[0:32]; L1: Wih1[j, 0:64]
    float wh[64];   // Whh{g}[j, 0:64]
    float bias;
    {
        if (g) {
            const float* s0 = Wih1 + j * 64;
            #pragma unroll
            for (int r = 0; r < 16; ++r) {
                float4 v = ((const float4*)s0)[r];
                wx[4*r] = v.x; wx[4*r+1] = v.y; wx[4*r+2] = v.z; wx[4*r+3] = v.w;
            }
            const float* s1 = Whh1 + j * 64;
            #pragma unroll
            for (int r = 0; r < 16; ++r) {
                float4 v = ((const float4*)s1)[r];
                wh[4*r] = v.x; wh[4*r+1] = v.y; wh[4*r+2] = v.z; wh[4*r+3] = v.w;
            }
            bias = bih1[j] + bhh1[j];
        } else {
            const float* s0 = Wih0 + j * 32;
            #pragma unroll
            for (int r = 0; r < 8; ++r) {
                float4 v = ((const float4*)s0)[r];
                wx[4*r] = v.x; wx[4*r+1] = v.y; wx[4*r+2] = v.z; wx[4*r+3] = v.w;
            }
            const float* s1 = Whh0 + j * 64;
            #pragma unroll
            for (int r = 0; r < 16; ++r) {
                float4 v = ((const float4*)s1)[r];
                wh[4*r] = v.x; wh[4*r+1] = v.y; wh[4*r+2] = v.z; wh[4*r+3] = v.w;
            }
            bias = bih0[j] + bhh0[j];
        }
    }

    // ---- state init ----
    float creg = 0.f, hreg = 0.f, pb = 0.f, whv = 0.f, bhs = 0.f;
    if (tid < 64) {                       // wave 0: layer-0 cell state owner (unit = tid)
        creg = c_in[b * 64 + tid];
        hreg = h_in[b * 64 + tid];
        h0buf[1][tid] = hreg;             // h0(-1)
    } else if (tid < 128) {
        h1buf[1][lane] = h_in[16384 + b * 64 + lane];   // h1(-1)
    }
    if (tid >= 256 && tid < 320) {        // wave 4: layer-1 cell state owner
        creg = c_in[16384 + b * 64 + lane];
        hreg = h_in[16384 + b * 64 + lane];
        whv  = Wh[lane];
        bhs  = bh[0];
    }
    // x chunk 0 -> xs[0]
    {
        int flat = tid * 4; int tt = flat >> 5; int i0 = flat & 31;
        float4 v = *(const float4*)&x[(size_t)b * SS * II + tt * II + i0];
        *(float4*)&xs[0][tt][i0] = v;
    }
    __syncthreads();

    // ---- main loop: iteration `it`: layer0 computes step it, layer1 computes step it-1 ----
    #pragma unroll 1
    for (int it = 0; it <= SS; ++it) {
        // ======== phase A: gate dots ========
        const bool activeA = g ? (it >= 1) : (it < SS);
        if (activeA) {
            const float* hA = &h0buf[(it + 1) & 1][0];   // h0(it-1): L0's prev-h, L1's input
            float a0 = 0.f, a1 = 0.f, a2 = 0.f, a3 = 0.f;
            if (g == 0) {
                const float* xr = &xs[(it >> 6) & 1][it & 63][0];
                #pragma unroll
                for (int r = 0; r < 8; ++r) {
                    float4 v = ((const float4*)xr)[r];
                    a0 += wx[4*r]   * v.x; a1 += wx[4*r+1] * v.y;
                    a2 += wx[4*r+2] * v.z; a3 += wx[4*r+3] * v.w;
                }
            } else {
                #pragma unroll
                for (int r = 0; r < 16; ++r) {
                    float4 v = ((const float4*)hA)[r];
                    a0 += wx[4*r]   * v.x; a1 += wx[4*r+1] * v.y;
                    a2 += wx[4*r+2] * v.z; a3 += wx[4*r+3] * v.w;
                }
            }
            const float* hr = g ? &h1buf[it & 1][0] : hA;  // recurrent operand
            #pragma unroll
            for (int r = 0; r < 16; ++r) {
                float4 v = ((const float4*)hr)[r];
                a0 += wh[4*r]   * v.x; a1 += wh[4*r+1] * v.y;
                a2 += wh[4*r+2] * v.z; a3 += wh[4*r+3] * v.w;
            }
            float acc = bias + ((a0 + a1) + (a2 + a3));
            float val = (wv == 2) ? tanhf(acc) : sigm(acc);
            gates[g][j] = val;
        }
        __syncthreads();

        // ======== phase B: cell/hidden update + head ========
        if (tid < 64 && it < SS) {
            float gi = gates[0][tid], gf = gates[0][64 + tid];
            float gg = gates[0][128 + tid], go = gates[0][192 + tid];
            creg = gf * creg + gi * gg;
            hreg = go * tanhf(creg);
            h0buf[it & 1][tid] = hreg;                    // h0(it)
        }
        if (tid >= 256 && tid < 320 && it >= 1) {
            float gi = gates[1][lane], gf = gates[1][64 + lane];
            float gg = gates[1][128 + lane], go = gates[1][192 + lane];
            creg = gf * creg + gi * gg;
            hreg = go * tanhf(creg);
            h1buf[(it + 1) & 1][lane] = hreg;             // h1(it-1)
            // head: probs[b, it-1] = sigmoid(dot(h1, Wh) + bh)
            float p = hreg * whv;
            p += __shfl_xor(p, 1);
            p += __shfl_xor(p, 2);
            p += __shfl_xor(p, 4);
            p += __shfl_xor(p, 8);
            p += __shfl_xor(p, 16);
            p += __shfl_xor(p, 32);
            p = sigm(p + bhs);
            const int t1 = it - 1;
            if ((t1 & 63) == lane) pb = p;                // rotate-latch for coalesced store
            if ((t1 & 63) == 63) out[b * SS + (t1 & ~63) + lane] = pb;
        }
        // x chunk prefetch: at chunk boundary, load next chunk into the other buffer
        if ((it & 63) == 0 && it + 64 < SS) {
            const int cn = (it >> 6) + 1;
            int flat = tid * 4; int tt = flat >> 5; int i0 = flat & 31;
            float4 v = *(const float4*)&x[(size_t)b * SS * II + (cn * 64 + tt) * II + i0];
            *(float4*)&xs[cn & 1][tt][i0] = v;
        }
        __syncthreads();
    }

    // ---- final states: h = stack(h0,h1) at out+524288, c at out+557056 ----
    if (tid < 64) {
        out[524288 + b * 64 + tid]         = hreg;   // h[0][b][:]
        out[524288 + 32768 + b * 64 + tid] = creg;   // c[0][b][:]
    }
    if (tid >= 256 && tid < 320) {
        out[524288 + 16384 + b * 64 + lane]         = hreg;   // h[1][b][:]
        out[524288 + 32768 + 16384 + b * 64 + lane] = creg;   // c[1][b][:]
    }
}

extern "C" void kernel_launch(void* const* d_in, const int* in_sizes, int n_in,
                              void* d_out, int out_size, void* d_ws, size_t ws_size,
                              hipStream_t stream) {
    const float* x    = (const float*)d_in[0];
    const float* h0   = (const float*)d_in[1];
    const float* c0   = (const float*)d_in[2];
    const float* Wih0 = (const float*)d_in[3];
    const float* Whh0 = (const float*)d_in[4];
    const float* bih0 = (const float*)d_in[5];
    const float* bhh0 = (const float*)d_in[6];
    const float* Wih1 = (const float*)d_in[7];
    const float* Whh1 = (const float*)d_in[8];
    const float* bih1 = (const float*)d_in[9];
    const float* bhh1 = (const float*)d_in[10];
    const float* Wh   = (const float*)d_in[11];
    const float* bh   = (const float*)d_in[12];
    float* out = (float*)d_out;

    hipLaunchKernelGGL(lstm_fused, dim3(BB), dim3(512), 0, stream,
                       x, h0, c0, Wih0, Whh0, bih0, bhh0,
                       Wih1, Whh1, bih1, bhh1, Wh, bh, out);
}

// Round 4
// 2376.935 us; speedup vs baseline: 1.1233x; 1.1233x over previous
//
#include <hip/hip_runtime.h>
#include <math.h>
#include <stdint.h>

#define SS 2048
#define II 32

typedef _Float16 f16x2 __attribute__((ext_vector_type(2)));
typedef __fp16   g16x2 __attribute__((ext_vector_type(2)));

union uhc { uint32_t u; f16x2 a; g16x2 b; };

__device__ __forceinline__ uint32_t pk(float x, float y) {
    uhc c; c.b = __builtin_amdgcn_cvt_pkrtz(x, y); return c.u;
}

__device__ __forceinline__ float fdot2(uint32_t a, uint32_t b, float c) {
    uhc x, y; x.u = a; y.u = b;
#if __has_builtin(__builtin_amdgcn_fdot2)
    return __builtin_amdgcn_fdot2(x.a, y.a, c, false);
#else
    return c + (float)x.a.x * (float)y.a.x + (float)x.a.y * (float)y.a.y;
#endif
}
__device__ __forceinline__ uint32_t rlu(uint32_t v, int k) {
    return (uint32_t)__builtin_amdgcn_readlane((int)v, k);
}
__device__ __forceinline__ float sigm(float x) {
    return __builtin_amdgcn_rcpf(1.f + __expf(-x));
}
__device__ __forceinline__ float tanh_(float x) {
    x = fminf(fmaxf(x, -15.f), 15.f);
    float e = __expf(-2.f * x);
    return (1.f - e) * __builtin_amdgcn_rcpf(1.f + e);
}

// Replicated cell update: lanes 0-31 own L0 unit pairs, lanes 32-63 own L1.
__device__ __forceinline__ void cell_update(const float* gbp, int it, int lane,
                                            float& c_lo, float& c_hi,
                                            float& h_lo, float& h_hi, uint32_t& hpk) {
    const int q = lane & 31, L = lane >> 5;
    const float* g = gbp + L * 257;
    float i0 = g[0 * 64 + 2 * q], i1 = g[0 * 64 + 2 * q + 1];
    float f0 = g[1 * 64 + 2 * q], f1 = g[1 * 64 + 2 * q + 1];
    float G0 = g[2 * 64 + 2 * q], G1 = g[2 * 64 + 2 * q + 1];
    float o0 = g[3 * 64 + 2 * q], o1 = g[3 * 64 + 2 * q + 1];
    const bool valid = L ? (it >= 1) : (it < SS);
    float nc0 = f0 * c_lo + i0 * G0;
    float nc1 = f1 * c_hi + i1 * G1;
    float nh0 = o0 * tanh_(nc0);
    float nh1 = o1 * tanh_(nc1);
    if (valid) { c_lo = nc0; c_hi = nc1; h_lo = nh0; h_hi = nh1; hpk = pk(nh0, nh1); }
}

__global__ __launch_bounds__(512, 2) void lstm_fused(
    const float* __restrict__ x,
    const float* __restrict__ h_in, const float* __restrict__ c_in,
    const float* __restrict__ Wih0, const float* __restrict__ Whh0,
    const float* __restrict__ bih0, const float* __restrict__ bhh0,
    const float* __restrict__ Wih1, const float* __restrict__ Whh1,
    const float* __restrict__ bih1, const float* __restrict__ bhh1,
    const float* __restrict__ Wh, const float* __restrict__ bh,
    float* __restrict__ out)
{
    __shared__ float gb[2][515];        // [parity][L*257 + gtype*64 + unit]; 257 = odd-bank offset
    __shared__ uint32_t xs[2][64][16];  // packed half2 x chunks (64 steps x 32 vals)

    const int b = blockIdx.x, tid = threadIdx.x;
    const int w = tid >> 6, lane = tid & 63;
    const int q = lane & 31, L = lane >> 5;

    // replicated h/c state: lane<32 -> layer0 units (2q,2q+1); lane>=32 -> layer1
    float2 hv = *(const float2*)&h_in[L * 16384 + b * 64 + 2 * q];
    float2 cv = *(const float2*)&c_in[L * 16384 + b * 64 + 2 * q];
    float c_lo = cv.x, c_hi = cv.y, h_lo = hv.x, h_hi = hv.y;
    uint32_t hpk = pk(h_lo, h_hi);

    const float* xb = x + (size_t)b * SS * II;
    {   // stage chunk 0 (packed f16)
        const float4 v = *(const float4*)(xb + (tid >> 3) * II + (tid & 7) * 4);
        xs[0][tid >> 3][(tid & 7) * 2]     = pk(v.x, v.y);
        xs[0][tid >> 3][(tid & 7) * 2 + 1] = pk(v.z, v.w);
    }

    if (w < 4) {
        // ================= layer-0 gate role: row = gtype*64 + unit =================
        const int row = w * 64 + lane;
        uint32_t wx[16], wh[32];
        {
            const float4* s = (const float4*)(Wih0 + row * 32);
            #pragma unroll
            for (int r = 0; r < 8; ++r) { float4 v = s[r]; wx[2*r] = pk(v.x, v.y); wx[2*r+1] = pk(v.z, v.w); }
        }
        {
            const float4* s = (const float4*)(Whh0 + row * 64);
            #pragma unroll
            for (int r = 0; r < 16; ++r) { float4 v = s[r]; wh[2*r] = pk(v.x, v.y); wh[2*r+1] = pk(v.z, v.w); }
        }
        const float bias = bih0[row] + bhh0[row];
        __syncthreads();

        #pragma unroll 1
        for (int it = 0; it <= SS; ++it) {
            const int p = it & 1;
            if (it < SS) {
                const uint32_t xv = xs[(it >> 6) & 1][it & 63][lane & 15];
                float a0 = bias, a1 = 0.f, a2 = 0.f, a3 = 0.f;
                #pragma unroll
                for (int k = 0; k < 16; k += 4) {
                    a0 = fdot2(wx[k+0], rlu(xv, k+0), a0);
                    a1 = fdot2(wx[k+1], rlu(xv, k+1), a1);
                    a2 = fdot2(wx[k+2], rlu(xv, k+2), a2);
                    a3 = fdot2(wx[k+3], rlu(xv, k+3), a3);
                }
                #pragma unroll
                for (int k = 0; k < 32; k += 4) {
                    a0 = fdot2(wh[k+0], rlu(hpk, k+0), a0);
                    a1 = fdot2(wh[k+1], rlu(hpk, k+1), a1);
                    a2 = fdot2(wh[k+2], rlu(hpk, k+2), a2);
                    a3 = fdot2(wh[k+3], rlu(hpk, k+3), a3);
                }
                const float acc = (a0 + a1) + (a2 + a3);
                gb[p][w * 64 + lane] = (w == 2) ? tanh_(acc) : sigm(acc);
            }
            __syncthreads();
            cell_update(gb[p], it, lane, c_lo, c_hi, h_lo, h_hi, hpk);
            if ((it & 63) == 0 && it + 64 < SS) {
                const int cn = (it >> 6) + 1;
                const float4 v = *(const float4*)(xb + (cn * 64 + (tid >> 3)) * II + (tid & 7) * 4);
                xs[cn & 1][tid >> 3][(tid & 7) * 2]     = pk(v.x, v.y);
                xs[cn & 1][tid >> 3][(tid & 7) * 2 + 1] = pk(v.z, v.w);
            }
        }
    } else {
        // ================= layer-1 gate role (skewed 1 step) =================
        const int row = (w - 4) * 64 + lane;
        uint32_t wi[32], wh[32];
        {
            const float4* s = (const float4*)(Wih1 + row * 64);
            #pragma unroll
            for (int r = 0; r < 16; ++r) { float4 v = s[r]; wi[2*r] = pk(v.x, v.y); wi[2*r+1] = pk(v.z, v.w); }
        }
        {
            const float4* s = (const float4*)(Whh1 + row * 64);
            #pragma unroll
            for (int r = 0; r < 16; ++r) { float4 v = s[r]; wh[2*r] = pk(v.x, v.y); wh[2*r+1] = pk(v.z, v.w); }
        }
        const float bias = bih1[row] + bhh1[row];
        const float whl = Wh[2 * q], whh_ = Wh[2 * q + 1], bhs = bh[0];
        float pb = 0.f;
        __syncthreads();

        #pragma unroll 1
        for (int it = 0; it <= SS; ++it) {
            const int p = it & 1;
            if (it >= 1) {
                float a0 = bias, a1 = 0.f, a2 = 0.f, a3 = 0.f;
                #pragma unroll
                for (int k = 0; k < 32; k += 4) {   // input = h0 (lanes 0-31)
                    a0 = fdot2(wi[k+0], rlu(hpk, k+0), a0);
                    a1 = fdot2(wi[k+1], rlu(hpk, k+1), a1);
                    a2 = fdot2(wi[k+2], rlu(hpk, k+2), a2);
                    a3 = fdot2(wi[k+3], rlu(hpk, k+3), a3);
                }
                #pragma unroll
                for (int k = 0; k < 32; k += 4) {   // recurrent = h1 (lanes 32-63)
                    a0 = fdot2(wh[k+0], rlu(hpk, 32+k+0), a0);
                    a1 = fdot2(wh[k+1], rlu(hpk, 32+k+1), a1);
                    a2 = fdot2(wh[k+2], rlu(hpk, 32+k+2), a2);
                    a3 = fdot2(wh[k+3], rlu(hpk, 32+k+3), a3);
                }
                const float acc = (a0 + a1) + (a2 + a3);
                gb[p][257 + (w - 4) * 64 + lane] = (w == 6) ? tanh_(acc) : sigm(acc);
            }
            __syncthreads();
            cell_update(gb[p], it, lane, c_lo, c_hi, h_lo, h_hi, hpk);
            if ((it & 63) == 0 && it + 64 < SS) {
                const int cn = (it >> 6) + 1;
                const float4 v = *(const float4*)(xb + (cn * 64 + (tid >> 3)) * II + (tid & 7) * 4);
                xs[cn & 1][tid >> 3][(tid & 7) * 2]     = pk(v.x, v.y);
                xs[cn & 1][tid >> 3][(tid & 7) * 2 + 1] = pk(v.z, v.w);
            }
            if (w == 7 && it >= 1) {
                // head: probs[b, it-1] from replicated h1 (lanes 32-63, 2 units/lane)
                float pv = h_lo * whl + h_hi * whh_;
                pv += __shfl_xor(pv, 1);
                pv += __shfl_xor(pv, 2);
                pv += __shfl_xor(pv, 4);
                pv += __shfl_xor(pv, 8);
                pv += __shfl_xor(pv, 16);
                pv = sigm(pv + bhs);
                const int t1 = it - 1;
                if (lane >= 32 && (t1 & 31) == lane - 32) pb = pv;
                if ((t1 & 31) == 31 && lane >= 32)
                    out[b * SS + (t1 & ~31) + (lane - 32)] = pb;
            }
        }
    }

    // final states: h at 524288 (2,256,64), c at 557056
    if (w == 0) {
        *(float2*)&out[524288 + L * 16384 + b * 64 + 2 * q] = make_float2(h_lo, h_hi);
        *(float2*)&out[557056 + L * 16384 + b * 64 + 2 * q] = make_float2(c_lo, c_hi);
    }
}

extern "C" void kernel_launch(void* const* d_in, const int* in_sizes, int n_in,
                              void* d_out, int out_size, void* d_ws, size_t ws_size,
                              hipStream_t stream) {
    const float* x    = (const float*)d_in[0];
    const float* h0   = (const float*)d_in[1];
    const float* c0   = (const float*)d_in[2];
    const float* Wih0 = (const float*)d_in[3];
    const float* Whh0 = (const float*)d_in[4];
    const float* bih0 = (const float*)d_in[5];
    const float* bhh0 = (const float*)d_in[6];
    const float* Wih1 = (const float*)d_in[7];
    const float* Whh1 = (const float*)d_in[8];
    const float* bih1 = (const float*)d_in[9];
    const float* bhh1 = (const float*)d_in[10];
    const float* Wh   = (const float*)d_in[11];
    const float* bh   = (const float*)d_in[12];
    float* out = (float*)d_out;

    hipLaunchKernelGGL(lstm_fused, dim3(256), dim3(512), 0, stream,
                       x, h0, c0, Wih0, Whh0, bih0, bhh0,
                       Wih1, Whh1, bih1, bhh1, Wh, bh, out);
}

// Round 5
// 1964.396 us; speedup vs baseline: 1.3593x; 1.2100x over previous
//
#include <hip/hip_runtime.h>
#include <math.h>
#include <stdint.h>

#define SS 2048
#define II 32

typedef _Float16 f16x2 __attribute__((ext_vector_type(2)));
typedef __fp16   g16x2 __attribute__((ext_vector_type(2)));

union uhc { uint32_t u; f16x2 a; g16x2 b; };

__device__ __forceinline__ uint32_t pk(float x, float y) {
    uhc c; c.b = __builtin_amdgcn_cvt_pkrtz(x, y); return c.u;
}

__device__ __forceinline__ float fdot2(uint32_t a, uint32_t b, float c) {
    uhc x, y; x.u = a; y.u = b;
#if __has_builtin(__builtin_amdgcn_fdot2)
    return __builtin_amdgcn_fdot2(x.a, y.a, c, false);
#else
    return c + (float)x.a.x * (float)y.a.x + (float)x.a.y * (float)y.a.y;
#endif
}
__device__ __forceinline__ float sigm(float x) {
    return __builtin_amdgcn_rcpf(1.f + __expf(-x));
}
__device__ __forceinline__ float tanh_(float x) {
    x = fminf(fmaxf(x, -15.f), 15.f);
    float e = __expf(-2.f * x);
    return (1.f - e) * __builtin_amdgcn_rcpf(1.f + e);
}

__global__ __launch_bounds__(512, 2) void lstm_fused(
    const float* __restrict__ x,
    const float* __restrict__ h_in, const float* __restrict__ c_in,
    const float* __restrict__ Wih0, const float* __restrict__ Whh0,
    const float* __restrict__ bih0, const float* __restrict__ bhh0,
    const float* __restrict__ Wih1, const float* __restrict__ Whh1,
    const float* __restrict__ bih1, const float* __restrict__ bhh1,
    const float* __restrict__ Wh, const float* __restrict__ bh,
    float* __restrict__ out)
{
    __shared__ float    gb[2][512];            // [parity][L*256 + gtype*64 + unit]
    __shared__ uint32_t h0w[2][32];            // packed half2 h0 (word u = units 2u,2u+1)
    __shared__ uint32_t h1w[2][32];
    __shared__ uint32_t xs[2][64][16];         // packed half2 x chunks

    const int b = blockIdx.x, tid = threadIdx.x;
    const int w = tid >> 6, lane = tid & 63;

    const float* xb = x + (size_t)b * SS * II;

    // ---- cell state: wave 0 owns L0 (unit = lane), wave 1 owns L1 ----
    float creg = 0.f, hreg = 0.f;
    if (w == 0) {
        hreg = h_in[b * 64 + lane];
        creg = c_in[b * 64 + lane];
        float o = __shfl_xor(hreg, 1);
        if (!(lane & 1)) h0w[0][lane >> 1] = pk(hreg, o);   // h0(-1), read at it=0
    }
    if (w == 1) {
        hreg = h_in[16384 + b * 64 + lane];
        creg = c_in[16384 + b * 64 + lane];
        float o = __shfl_xor(hreg, 1);
        if (!(lane & 1)) h1w[1][lane >> 1] = pk(hreg, o);   // h1(-1), read at it=1
    }

    // ---- stage x chunk 0 ----
    {
        const float4 v = *(const float4*)(xb + (tid >> 3) * II + (tid & 7) * 4);
        xs[0][tid >> 3][(tid & 7) * 2]     = pk(v.x, v.y);
        xs[0][tid >> 3][(tid & 7) * 2 + 1] = pk(v.z, v.w);
    }

    if (w < 4) {
        // ========== L0 gate waves: gate row = w*64 + lane (gtype = w) ==========
        uint32_t wxx[16], whh[32];
        {
            const float4* s = (const float4*)(Wih0 + (w * 64 + lane) * 32);
            #pragma unroll
            for (int r = 0; r < 8; ++r) { float4 v = s[r]; wxx[2*r] = pk(v.x, v.y); wxx[2*r+1] = pk(v.z, v.w); }
        }
        {
            const float4* s = (const float4*)(Whh0 + (w * 64 + lane) * 64);
            #pragma unroll
            for (int r = 0; r < 16; ++r) { float4 v = s[r]; whh[2*r] = pk(v.x, v.y); whh[2*r+1] = pk(v.z, v.w); }
        }
        const float bias = bih0[w * 64 + lane] + bhh0[w * 64 + lane];
        // w1 doubles as L1 cell wave + head
        float whv = 0.f, bhs = 0.f, pb = 0.f;
        if (w == 1) { whv = Wh[lane]; bhs = bh[0]; }
        __syncthreads();

        #pragma unroll 1
        for (int it = 0; it <= SS; ++it) {
            const int p = it & 1;
            if (it < SS) {
                uint32_t hw[32], xw[16];
                {
                    const uint4* hs = (const uint4*)h0w[p];
                    uint4* d = (uint4*)hw;
                    #pragma unroll
                    for (int r = 0; r < 8; ++r) d[r] = hs[r];
                    const uint4* xsrc = (const uint4*)xs[(it >> 6) & 1][it & 63];
                    uint4* xd = (uint4*)xw;
                    #pragma unroll
                    for (int r = 0; r < 4; ++r) xd[r] = xsrc[r];
                }
                float a0 = bias, a1 = 0.f, a2 = 0.f, a3 = 0.f;
                #pragma unroll
                for (int k = 0; k < 16; k += 4) {
                    a0 = fdot2(wxx[k+0], xw[k+0], a0);
                    a1 = fdot2(wxx[k+1], xw[k+1], a1);
                    a2 = fdot2(wxx[k+2], xw[k+2], a2);
                    a3 = fdot2(wxx[k+3], xw[k+3], a3);
                }
                #pragma unroll
                for (int k = 0; k < 32; k += 4) {
                    a0 = fdot2(whh[k+0], hw[k+0], a0);
                    a1 = fdot2(whh[k+1], hw[k+1], a1);
                    a2 = fdot2(whh[k+2], hw[k+2], a2);
                    a3 = fdot2(whh[k+3], hw[k+3], a3);
                }
                const float acc = (a0 + a1) + (a2 + a3);
                gb[p][w * 64 + lane] = (w == 2) ? tanh_(acc) : sigm(acc);
            }
            if ((it & 63) == 0 && it + 64 < SS) {
                const int cn = (it >> 6) + 1;
                const float4 v = *(const float4*)(xb + (cn * 64 + (tid >> 3)) * II + (tid & 7) * 4);
                xs[cn & 1][tid >> 3][(tid & 7) * 2]     = pk(v.x, v.y);
                xs[cn & 1][tid >> 3][(tid & 7) * 2 + 1] = pk(v.z, v.w);
            }
            __syncthreads();

            // ---- phase 2: cell updates ----
            if (w == 0 && it < SS) {            // L0 cell: h0(it)
                float gi = gb[p][lane],       gf = gb[p][64 + lane];
                float gg = gb[p][128 + lane], go = gb[p][192 + lane];
                creg = gf * creg + gi * gg;
                hreg = go * tanh_(creg);
                float o = __shfl_xor(hreg, 1);
                if (!(lane & 1)) h0w[(it + 1) & 1][lane >> 1] = pk(hreg, o);
            }
            if (w == 1 && it >= 1) {            // L1 cell: h1(it-1) + head
                float gi = gb[p][256 + lane],       gf = gb[p][320 + lane];
                float gg = gb[p][384 + lane],       go = gb[p][448 + lane];
                creg = gf * creg + gi * gg;
                hreg = go * tanh_(creg);
                float o = __shfl_xor(hreg, 1);
                if (!(lane & 1)) h1w[(it + 1) & 1][lane >> 1] = pk(hreg, o);
                float pv = hreg * whv;
                pv += __shfl_xor(pv, 1);
                pv += __shfl_xor(pv, 2);
                pv += __shfl_xor(pv, 4);
                pv += __shfl_xor(pv, 8);
                pv += __shfl_xor(pv, 16);
                pv += __shfl_xor(pv, 32);
                pv = sigm(pv + bhs);
                const int t1 = it - 1;
                if ((t1 & 63) == lane) pb = pv;
                if ((t1 & 63) == 63) out[b * SS + (t1 & ~63) + lane] = pb;
            }
            __syncthreads();
        }
    } else {
        // ========== L1 gate waves: gate row = (w-4)*64 + lane ==========
        const int row = (w - 4) * 64 + lane;
        uint32_t wA[32], wB[32];
        {
            const float4* s = (const float4*)(Wih1 + row * 64);
            #pragma unroll
            for (int r = 0; r < 16; ++r) { float4 v = s[r]; wA[2*r] = pk(v.x, v.y); wA[2*r+1] = pk(v.z, v.w); }
        }
        {
            const float4* s = (const float4*)(Whh1 + row * 64);
            #pragma unroll
            for (int r = 0; r < 16; ++r) { float4 v = s[r]; wB[2*r] = pk(v.x, v.y); wB[2*r+1] = pk(v.z, v.w); }
        }
        const float bias = bih1[row] + bhh1[row];
        __syncthreads();

        #pragma unroll 1
        for (int it = 0; it <= SS; ++it) {
            const int p = it & 1;
            if (it >= 1) {
                uint32_t h0r[32], h1r[32];
                {
                    const uint4* s0 = (const uint4*)h0w[p];    // h0(it-1) = input at t=it-1
                    uint4* d0 = (uint4*)h0r;
                    #pragma unroll
                    for (int r = 0; r < 8; ++r) d0[r] = s0[r];
                    const uint4* s1 = (const uint4*)h1w[p];    // h1(it-2) = recurrent at t=it-1
                    uint4* d1 = (uint4*)h1r;
                    #pragma unroll
                    for (int r = 0; r < 8; ++r) d1[r] = s1[r];
                }
                float a0 = bias, a1 = 0.f, a2 = 0.f, a3 = 0.f;
                #pragma unroll
                for (int k = 0; k < 32; k += 4) {
                    a0 = fdot2(wA[k+0], h0r[k+0], a0);
                    a1 = fdot2(wA[k+1], h0r[k+1], a1);
                    a2 = fdot2(wA[k+2], h0r[k+2], a2);
                    a3 = fdot2(wA[k+3], h0r[k+3], a3);
                }
                #pragma unroll
                for (int k = 0; k < 32; k += 4) {
                    a0 = fdot2(wB[k+0], h1r[k+0], a0);
                    a1 = fdot2(wB[k+1], h1r[k+1], a1);
                    a2 = fdot2(wB[k+2], h1r[k+2], a2);
                    a3 = fdot2(wB[k+3], h1r[k+3], a3);
                }
                const float acc = (a0 + a1) + (a2 + a3);
                gb[p][256 + row] = (w == 6) ? tanh_(acc) : sigm(acc);
            }
            if ((it & 63) == 0 && it + 64 < SS) {
                const int cn = (it >> 6) + 1;
                const float4 v = *(const float4*)(xb + (cn * 64 + (tid >> 3)) * II + (tid & 7) * 4);
                xs[cn & 1][tid >> 3][(tid & 7) * 2]     = pk(v.x, v.y);
                xs[cn & 1][tid >> 3][(tid & 7) * 2 + 1] = pk(v.z, v.w);
            }
            __syncthreads();
            // phase 2: no role for L1 gate waves
            __syncthreads();
        }
    }

    // ---- final states: h at 524288 (2,256,64), c at 557056 ----
    if (w == 0) {
        out[524288 + b * 64 + lane] = hreg;            // h[0]
        out[557056 + b * 64 + lane] = creg;            // c[0]
    }
    if (w == 1) {
        out[524288 + 16384 + b * 64 + lane] = hreg;    // h[1]
        out[557056 + 16384 + b * 64 + lane] = creg;    // c[1]
    }
}

extern "C" void kernel_launch(void* const* d_in, const int* in_sizes, int n_in,
                              void* d_out, int out_size, void* d_ws, size_t ws_size,
                              hipStream_t stream) {
    const float* x    = (const float*)d_in[0];
    const float* h0   = (const float*)d_in[1];
    const float* c0   = (const float*)d_in[2];
    const float* Wih0 = (const float*)d_in[3];
    const float* Whh0 = (const float*)d_in[4];
    const float* bih0 = (const float*)d_in[5];
    const float* bhh0 = (const float*)d_in[6];
    const float* Wih1 = (const float*)d_in[7];
    const float* Whh1 = (const float*)d_in[8];
    const float* bih1 = (const float*)d_in[9];
    const float* bhh1 = (const float*)d_in[10];
    const float* Wh   = (const float*)d_in[11];
    const float* bh   = (const float*)d_in[12];
    float* out = (float*)d_out;

    hipLaunchKernelGGL(lstm_fused, dim3(256), dim3(512), 0, stream,
                       x, h0, c0, Wih0, Whh0, bih0, bhh0,
                       Wih1, Whh1, bih1, bhh1, Wh, bh, out);
}